// Round 5
// baseline (29.022 us; speedup 1.0000x reference)
//
#include <hip/hip_runtime.h>

#define TT 4096
#define DD 256

typedef __attribute__((ext_vector_type(8))) short short8;
typedef __attribute__((ext_vector_type(4))) float f32x4;
typedef __attribute__((ext_vector_type(2))) unsigned int u32x2;
typedef __attribute__((ext_vector_type(4))) unsigned int u32x4;

__device__ __forceinline__ unsigned int f2bf(float f) {
    unsigned int u = __builtin_bit_cast(unsigned int, f);
    u += 0x7fffu + ((u >> 16) & 1u);          // RNE
    return u >> 16;
}

#define GLDS16(g, l) __builtin_amdgcn_global_load_lds(                         \
    (const __attribute__((address_space(1))) void*)(g),                        \
    (__attribute__((address_space(3))) void*)(l), 16, 0, 0)

// ---------------- kPre: W fp32 -> bf16 copy (once) ----------------
__global__ __launch_bounds__(256)
void kPre(const float* __restrict__ Win, unsigned short* __restrict__ Wbf) {
    int i = (blockIdx.x * 256 + threadIdx.x) * 4;
    float4 v = *(const float4*)(Win + i);
    u32x2 p;
    p.x = f2bf(v.x) | (f2bf(v.y) << 16);
    p.y = f2bf(v.z) | (f2bf(v.w) << 16);
    *(u32x2*)(Wbf + i) = p;
}

// ---------------- kA: zw[b][n][t] = w[t]*(x@W^T + b)  (bf16, transposed) ----
__global__ __launch_bounds__(256, 4)
void kA(const float* __restrict__ x, const float* __restrict__ mask,
        const unsigned short* __restrict__ Wbf, const float* __restrict__ bin,
        unsigned short* __restrict__ zw)
{
    __shared__ union {
        unsigned short xl[2][32][64];   // x tile bf16, XOR-quarter swizzled (8 KB)
        unsigned short T[128][32];      // epilogue transpose buffer (8 KB)
    } U;
    __shared__ unsigned short Wl[2][128][64];  // W chunks, linear (glds dest), 32 KB

    const int tid  = threadIdx.x;
    const int cpx  = gridDim.x >> 3;
    const int wg   = (blockIdx.x & 7) * cpx + (blockIdx.x >> 3);  // XCD-chunked
    const int np   = wg & 1;
    const int tile = wg >> 1;
    const int b    = tile >> 7;              // 128 tiles of 32 rows per batch
    const int r0   = (tile & 127) * 32;
    const int n0   = np * 128;

    const int w = tid >> 6, lane = tid & 63, lr = lane & 15, lg = lane >> 4;

    // x staging map: row = tid>>3 (32 rows), 8 cols per thread
    const int xrow = tid >> 3, xpart = tid & 7;
    const float* xsrc = x + ((size_t)(b * TT + r0 + xrow)) * DD + 8 * xpart;
    const int xqpos = (xpart ^ (xrow & 7)) * 8;

    const int wrow = lane >> 3, wq = lane & 7;

    float xr[8];
    auto xload = [&](int t) {
        const float4* p = (const float4*)(xsrc + 64 * t);
        float4 a = p[0], c = p[1];
        xr[0]=a.x; xr[1]=a.y; xr[2]=a.z; xr[3]=a.w;
        xr[4]=c.x; xr[5]=c.y; xr[6]=c.z; xr[7]=c.w;
    };
    auto xstore = [&](int buf) {
        u32x4 p;
        p.x = f2bf(xr[0]) | (f2bf(xr[1]) << 16);
        p.y = f2bf(xr[2]) | (f2bf(xr[3]) << 16);
        p.z = f2bf(xr[4]) | (f2bf(xr[5]) << 16);
        p.w = f2bf(xr[6]) | (f2bf(xr[7]) << 16);
        *(u32x4*)&U.xl[buf][xrow][xqpos] = p;
    };
    auto wstage = [&](int t, int buf) {     // pre-swizzled global src, linear LDS dest
        #pragma unroll
        for (int i = 0; i < 4; ++i) {
            int row = 32 * w + 8 * i + wrow;
            int sq  = wq ^ (row & 7);
            const unsigned short* g = Wbf + (size_t)(n0 + row) * DD + 64 * t + 8 * sq;
            GLDS16(g, &Wl[buf][32 * w + 8 * i][0]);
        }
    };

    f32x4 acc[2][2];
    #pragma unroll
    for (int m = 0; m < 2; ++m)
        #pragma unroll
        for (int nn = 0; nn < 2; ++nn) acc[m][nn] = (f32x4){0.f, 0.f, 0.f, 0.f};

    wstage(0, 0);
    xload(0);
    xstore(0);
    __syncthreads();

    #pragma unroll
    for (int t = 0; t < 4; ++t) {
        const int buf = t & 1;
        if (t < 3) { wstage(t + 1, buf ^ 1); xload(t + 1); }
        short8 af[2][2], bf[2][2];
        #pragma unroll
        for (int m = 0; m < 2; ++m)
            #pragma unroll
            for (int ks = 0; ks < 2; ++ks)
                af[m][ks] = *(const short8*)&U.xl[buf][16 * m + lr][(((4 * ks + lg) ^ (lr & 7))) * 8];
        #pragma unroll
        for (int nn = 0; nn < 2; ++nn)
            #pragma unroll
            for (int ks = 0; ks < 2; ++ks)
                bf[nn][ks] = *(const short8*)&Wl[buf][32 * w + 16 * nn + lr][(((4 * ks + lg) ^ (lr & 7))) * 8];
        #pragma unroll
        for (int ks = 0; ks < 2; ++ks)
            #pragma unroll
            for (int m = 0; m < 2; ++m)
                #pragma unroll
                for (int nn = 0; nn < 2; ++nn)
                    acc[m][nn] = __builtin_amdgcn_mfma_f32_16x16x32_bf16(af[m][ks], bf[nn][ks], acc[m][nn], 0, 0, 0);
        if (t < 3) xstore(buf ^ 1);
        __syncthreads();
    }

    // epilogue: (acc + bias) * w[t], bf16, transpose via LDS, store zw[b][n][t]
    const float INV_E = 0.36787944117144233f;
    float wvv[2][4];
    #pragma unroll
    for (int m = 0; m < 2; ++m)
        #pragma unroll
        for (int j = 0; j < 4; ++j)
            wvv[m][j] = __expf(mask[b * TT + r0 + 16 * m + 4 * lg + j] * INV_E);
    float bv[2];
    bv[0] = bin[n0 + 32 * w + lr];
    bv[1] = bin[n0 + 32 * w + 16 + lr];

    #pragma unroll
    for (int m = 0; m < 2; ++m)
        #pragma unroll
        for (int nn = 0; nn < 2; ++nn) {
            unsigned int q0 = f2bf((acc[m][nn][0] + bv[nn]) * wvv[m][0])
                            | (f2bf((acc[m][nn][1] + bv[nn]) * wvv[m][1]) << 16);
            unsigned int q1 = f2bf((acc[m][nn][2] + bv[nn]) * wvv[m][2])
                            | (f2bf((acc[m][nn][3] + bv[nn]) * wvv[m][3]) << 16);
            *(u32x2*)&U.T[32 * w + 16 * nn + lr][16 * m + 4 * lg] = (u32x2){q0, q1};
        }
    __syncthreads();
    {
        int row = tid >> 1, part = tid & 1;
        u32x4 va = *(const u32x4*)&U.T[row][16 * part];
        u32x4 vb = *(const u32x4*)&U.T[row][16 * part + 8];
        unsigned short* dst = zw + ((size_t)(b * DD + n0 + row)) * TT + r0 + 16 * part;
        *(u32x4*)(dst)     = va;
        *(u32x4*)(dst + 8) = vb;
    }
}

// ---------------- kB: out = Toeplitz(r^|i-t|) @ zw ----------------
#define LOG2R (-0.5307378454346229f)   // log2(exp(-1/e))

__global__ __launch_bounds__(256, 4)
void kB(const unsigned short* __restrict__ zw, float* __restrict__ out)
{
    __shared__ unsigned short ul[64][192];   // zw^T tile, XOR-quarter swizzled (24 KB)
    const int tid  = threadIdx.x;
    const int cpx  = gridDim.x >> 3;
    const int wg   = (blockIdx.x & 7) * cpx + (blockIdx.x >> 3);
    const int n0   = (wg & 3) * 64;
    const int tile = wg >> 2;
    const int b    = tile >> 6;              // 64 tiles of 64 rows per batch
    const int r0   = (tile & 63) * 64;
    const int t0   = r0 - 64;
    const int w = tid >> 6, lane = tid & 63, lr = lane & 15, lg = lane >> 4;

    // stage issue (T14: loads first, VALU af-build overlaps, writes last)
    short8 sv[6];
    const int srow = tid >> 2, spart = tid & 3;
    {
        const unsigned short* src = zw + ((size_t)(b * DD + n0 + srow)) * TT;
        #pragma unroll
        for (int i = 0; i < 6; ++i) {
            int q  = 4 * i + spart;
            int tq = t0 + 8 * q;
            short8 v = {0, 0, 0, 0, 0, 0, 0, 0};
            if (tq >= 0 && tq < TT) v = *(const short8*)(src + tq);
            sv[i] = v;
        }
    }

    // Toeplitz A-fragments in registers (48 exp2, hides load latency)
    short8 af[6];
    #pragma unroll
    for (int ch = 0; ch < 6; ++ch) {
        unsigned int p[4];
        #pragma unroll
        for (int pp = 0; pp < 4; ++pp) {
            int d0 = (16 * w + lr + 64) - (32 * ch + 8 * lg + 2 * pp);
            int d1 = d0 - 1;
            float f0 = exp2f(LOG2R * (float)((d0 < 0) ? -d0 : d0));
            float f1 = exp2f(LOG2R * (float)((d1 < 0) ? -d1 : d1));
            p[pp] = f2bf(f0) | (f2bf(f1) << 16);
        }
        af[ch] = __builtin_bit_cast(short8, (u32x4){p[0], p[1], p[2], p[3]});
    }

    #pragma unroll
    for (int i = 0; i < 6; ++i) {
        int q = 4 * i + spart;
        *(short8*)&ul[srow][(q ^ (srow & 7)) * 8] = sv[i];
    }
    __syncthreads();

    f32x4 acc[4];
    #pragma unroll
    for (int nn = 0; nn < 4; ++nn) acc[nn] = (f32x4){0.f, 0.f, 0.f, 0.f};

    #pragma unroll
    for (int ch = 0; ch < 6; ++ch) {
        short8 bfr[4];
        #pragma unroll
        for (int nn = 0; nn < 4; ++nn)
            bfr[nn] = *(const short8*)&ul[16 * nn + lr][(((4 * ch + lg) ^ (lr & 7))) * 8];
        #pragma unroll
        for (int nn = 0; nn < 4; ++nn)
            acc[nn] = __builtin_amdgcn_mfma_f32_16x16x32_bf16(af[ch], bfr[nn], acc[nn], 0, 0, 0);
    }

    float* ob = out + ((size_t)(b * TT + r0)) * DD;
    #pragma unroll
    for (int nn = 0; nn < 4; ++nn)
        #pragma unroll
        for (int j = 0; j < 4; ++j)
            ob[(16 * w + 4 * lg + j) * DD + n0 + 16 * nn + lr] = acc[nn][j];
}

extern "C" void kernel_launch(void* const* d_in, const int* in_sizes, int n_in,
                              void* d_out, int out_size, void* d_ws, size_t ws_size,
                              hipStream_t stream) {
    const float* x    = (const float*)d_in[0];
    const float* mask = (const float*)d_in[1];
    const float* Win  = (const float*)d_in[2];
    const float* bin  = (const float*)d_in[3];
    float* out = (float*)d_out;

    const int nb = in_sizes[0] / (TT * DD);                  // 4 batches
    unsigned short* zw  = (unsigned short*)d_ws;             // [nb][256][4096] bf16 (8 MiB)
    unsigned short* Wbf = (unsigned short*)((char*)d_ws + (8u << 20));

    hipLaunchKernelGGL(kPre, dim3(64), dim3(256), 0, stream, Win, Wbf);
    hipLaunchKernelGGL(kA, dim3(nb * 256), dim3(256), 0, stream, x, mask, Wbf, bin, zw);
    hipLaunchKernelGGL(kB, dim3(nb * 256), dim3(256), 0, stream, zw, out);
}